// Round 8
// baseline (146.565 us; speedup 1.0000x reference)
//
#include <hip/hip_runtime.h>
#include <hip/hip_fp16.h>

#define HD 8
#define CD 16
#define DIM 128
#define NEG_SLOPE 0.2f

static __device__ __forceinline__ float lrelu(float v){ return v > 0.f ? v : NEG_SLOPE*v; }

// ---------------- K1: h = x @ W (fp16 out), plus alpha_src/alpha_dst epilogue ----------------
// 64-node tile (max W reuse per block) + register double-buffer prefetch of W:
// the next k-step's 4 W float4s are issued before the current 128 FMAs, hiding the
// ~250cy L2 latency that serialized r6/r7 (W load sat at the head of each k-step chain).
__global__ __launch_bounds__(256) void k_gemm(const float* __restrict__ x,
    const float* __restrict__ W, const float* __restrict__ a_src_g, const float* __restrict__ a_dst_g,
    __half* __restrict__ hout, float* __restrict__ as_o, float* __restrict__ ad_o, int N)
{
  __shared__ float xs[64*DIM]; // 32 KB
  const int tid = threadIdx.x;
  const int c = tid & 31;
  const int r = tid >> 5;
  const long nbase = (long)blockIdx.x * 64;

  #pragma unroll
  for (int it = 0; it < 8; ++it){
    int lin = it*1024 + tid*4;
    long node = nbase + (lin >> 7);
    float4 v = make_float4(0.f,0.f,0.f,0.f);
    if (node < N) v = *(const float4*)(x + node*DIM + (lin & 127));
    *(float4*)(xs + lin) = v;
  }
  __syncthreads();

  float acc[8][4];
  #pragma unroll
  for (int i = 0; i < 8; ++i){ acc[i][0]=0.f; acc[i][1]=0.f; acc[i][2]=0.f; acc[i][3]=0.f; }

  const float* Wc = W + 4*c;
  float4 w0 = *(const float4*)(Wc + 0*DIM);
  float4 w1 = *(const float4*)(Wc + 1*DIM);
  float4 w2 = *(const float4*)(Wc + 2*DIM);
  float4 w3 = *(const float4*)(Wc + 3*DIM);

#define FMA_STEP(kk)                                                        \
  {                                                                         \
    _Pragma("unroll")                                                       \
    for (int i = 0; i < 8; ++i){                                            \
      float4 xv = *(const float4*)(xs + (r*8+i)*DIM + (kk));                \
      acc[i][0] += xv.x*w0.x + xv.y*w1.x + xv.z*w2.x + xv.w*w3.x;           \
      acc[i][1] += xv.x*w0.y + xv.y*w1.y + xv.z*w2.y + xv.w*w3.y;           \
      acc[i][2] += xv.x*w0.z + xv.y*w1.z + xv.z*w2.z + xv.w*w3.z;           \
      acc[i][3] += xv.x*w0.w + xv.y*w1.w + xv.z*w2.w + xv.w*w3.w;           \
    }                                                                       \
  }

  for (int k = 0; k < DIM-4; k += 4){
    float4 nw0 = *(const float4*)(Wc + (size_t)(k+4)*DIM);
    float4 nw1 = *(const float4*)(Wc + (size_t)(k+5)*DIM);
    float4 nw2 = *(const float4*)(Wc + (size_t)(k+6)*DIM);
    float4 nw3 = *(const float4*)(Wc + (size_t)(k+7)*DIM);
    FMA_STEP(k);
    w0 = nw0; w1 = nw1; w2 = nw2; w3 = nw3;
  }
  FMA_STEP(DIM-4);
#undef FMA_STEP

  float4 asv = *(const float4*)(a_src_g + 4*c);
  float4 adv = *(const float4*)(a_dst_g + 4*c);
  #pragma unroll
  for (int i = 0; i < 8; ++i){
    long node = nbase + r*8 + i;
    float ps = acc[i][0]*asv.x + acc[i][1]*asv.y + acc[i][2]*asv.z + acc[i][3]*asv.w;
    float pd = acc[i][0]*adv.x + acc[i][1]*adv.y + acc[i][2]*adv.z + acc[i][3]*adv.w;
    ps += __shfl_xor(ps, 1); ps += __shfl_xor(ps, 2);
    pd += __shfl_xor(pd, 1); pd += __shfl_xor(pd, 2);
    if (node < N){
      union { __half2 h2[2]; uint2 u; } pk;
      pk.h2[0] = __floats2half2_rn(acc[i][0], acc[i][1]);
      pk.h2[1] = __floats2half2_rn(acc[i][2], acc[i][3]);
      *(uint2*)(hout + node*DIM + 4*c) = pk.u;
      if ((c & 3) == 0){
        as_o[node*HD + (c>>2)] = ps;
        ad_o[node*HD + (c>>2)] = pd;
      }
    }
  }
}

// ---------------- CSR build ----------------
__global__ void k_count(const int* __restrict__ dst, int* __restrict__ cnt, int E){
  int e = blockIdx.x*256 + threadIdx.x;
  if (e < E) atomicAdd(&cnt[dst[e]], 1);
}

__global__ __launch_bounds__(256) void k_scan1(const int* __restrict__ cnt, int* __restrict__ bsum,
                                               int chunk, int N){
  __shared__ int tmp[256];
  int t = threadIdx.x;
  int base = blockIdx.x * chunk;
  int i = base + t;
  int v = (t < chunk && i < N) ? cnt[i] : 0;
  tmp[t] = v; __syncthreads();
  for (int off = 128; off > 0; off >>= 1){
    if (t < off) tmp[t] += tmp[t+off];
    __syncthreads();
  }
  if (t == 0) bsum[blockIdx.x] = tmp[0];
}

__global__ __launch_bounds__(256) void k_scan2(int* __restrict__ bsum, int* __restrict__ row_ofs, int N){
  __shared__ int tmp[256];
  int t = threadIdx.x;
  int v = bsum[t];
  tmp[t] = v; __syncthreads();
  for (int off = 1; off < 256; off <<= 1){
    int u = (t >= off) ? tmp[t-off] : 0;
    __syncthreads();
    tmp[t] += u;
    __syncthreads();
  }
  bsum[t] = tmp[t] - v;            // exclusive
  if (t == 255) row_ofs[N] = tmp[255];
}

__global__ __launch_bounds__(256) void k_scan3(const int* __restrict__ cnt, const int* __restrict__ bsum,
                                               int* __restrict__ row_ofs, int* __restrict__ wpos,
                                               int chunk, int N){
  __shared__ int tmp[256];
  int t = threadIdx.x;
  int base = blockIdx.x * chunk;
  int i = base + t;
  int v = (t < chunk && i < N) ? cnt[i] : 0;
  tmp[t] = v; __syncthreads();
  for (int off = 1; off < 256; off <<= 1){
    int u = (t >= off) ? tmp[t-off] : 0;
    __syncthreads();
    tmp[t] += u;
    __syncthreads();
  }
  int excl = tmp[t] - v;
  int bbase = bsum[blockIdx.x];
  if (t < chunk && i < N){
    row_ofs[i] = bbase + excl;
    wpos[i]    = bbase + excl;
  }
}

// scatter edges into CSR order — src index ONLY (weights recomputed in k_aggr).
__global__ void k_scatter(const int* __restrict__ src, const int* __restrict__ dst,
                          int* __restrict__ wpos, int* __restrict__ csr_src, int E){
  int e = blockIdx.x*256 + threadIdx.x;
  if (e >= E) return;
  int d = dst[e];
  int pos = atomicAdd(&wpos[d], 1);
  csr_src[pos] = src[e];
}

// ---------------- K4: weighted gather (fp16 h), weights computed per-lane ----------------
__global__ __launch_bounds__(256) void k_aggr(const __half* __restrict__ h,
    const float* __restrict__ as_, const float* __restrict__ ad_,
    const int* __restrict__ row_ofs, const int* __restrict__ csr_src,
    const float* __restrict__ bias, float* __restrict__ out, int N)
{
  const int n = blockIdx.x*4 + (threadIdx.x >> 6);
  if (n >= N) return;
  const int t  = threadIdx.x & 63;
  const int hb = t >> 3;
  const int off = t*2;

  const float ad_n = ad_[(size_t)n*HD + hb];
  const float w_self = __expf(lrelu(as_[(size_t)n*HD + hb] + ad_n));

  float sum = w_self;
  float2 hv = __half22float2(*(const __half2*)(h + (size_t)n*DIM + off));
  float2 acc; acc.x = w_self*hv.x; acc.y = w_self*hv.y;

  const int ofs = row_ofs[n];
  const int deg = row_ofs[n+1] - ofs;

  for (int jb = 0; jb < deg; jb += 16){
    const int c = deg - jb;               // valid slots this chunk (>=1)
    int s[16];
    #pragma unroll
    for (int q = 0; q < 16; ++q){
      int sq = csr_src[ofs + jb + q];     // padded: safe to over-read
      s[q] = (q < c) ? sq : n;
    }

    __half2 hq[16];                        // 16 independent gathers, 1 VGPR each
    #pragma unroll
    for (int q = 0; q < 16; ++q)
      hq[q] = *(const __half2*)(h + (size_t)s[q]*DIM + off);

    float w[16];
    #pragma unroll
    for (int q = 0; q < 16; ++q){
      float e = lrelu(as_[(size_t)s[q]*HD + hb] + ad_n);
      w[q] = (q < c) ? __expf(e) : 0.f;
    }

    #pragma unroll
    for (int q = 0; q < 16; ++q){
      float2 hf = __half22float2(hq[q]);
      sum   += w[q];
      acc.x += w[q]*hf.x;
      acc.y += w[q]*hf.y;
    }
  }

  const float2 bv = *(const float2*)(bias + off);
  const float inv = 1.0f / (sum + 1e-16f);
  float2 o;
  o.x = acc.x*inv + bv.x;
  o.y = acc.y*inv + bv.y;
  *(float2*)(out + (size_t)n*DIM + off) = o;
}

extern "C" void kernel_launch(void* const* d_in, const int* in_sizes, int n_in,
                              void* d_out, int out_size, void* d_ws, size_t ws_size,
                              hipStream_t stream)
{
  const float* x     = (const float*)d_in[0];
  const int*   ei    = (const int*)  d_in[1];
  const float* W     = (const float*)d_in[2];
  const float* a_src = (const float*)d_in[3];
  const float* a_dst = (const float*)d_in[4];
  const float* bias  = (const float*)d_in[5];
  float* out = (float*)d_out;

  const int N = in_sizes[0] / DIM;
  const int E = in_sizes[1] / 2;
  const int* src = ei;
  const int* dst = ei + E;

  char* w = (char*)d_ws;
  __half* h    = (__half*)w; w += (size_t)N*DIM*2;
  float* as_   = (float*)w; w += (size_t)N*HD*4;
  float* ad_   = (float*)w; w += (size_t)N*HD*4;
  int* csr_src = (int*)w;   w += (size_t)(E+16)*4;     // +16 pad for chunk over-read
  int* cnt     = (int*)w;   w += (size_t)N*4;
  int* wpos    = (int*)w;   w += (size_t)N*4;
  int* bsum    = (int*)w;   w += 256*4;
  int* row_ofs = (int*)w;   w += (size_t)(N+1)*4;

  const int chunk = (N + 255) / 256;   // 196 for N=50000 (must be <=256)

  hipLaunchKernelGGL(k_gemm,    dim3((N+63)/64),   dim3(256), 0, stream, x, W, a_src, a_dst, h, as_, ad_, N);
  hipMemsetAsync(cnt, 0, (size_t)N*4, stream);
  hipLaunchKernelGGL(k_count,   dim3((E+255)/256), dim3(256), 0, stream, dst, cnt, E);
  hipLaunchKernelGGL(k_scan1,   dim3(256),         dim3(256), 0, stream, cnt, bsum, chunk, N);
  hipLaunchKernelGGL(k_scan2,   dim3(1),           dim3(256), 0, stream, bsum, row_ofs, N);
  hipLaunchKernelGGL(k_scan3,   dim3(256),         dim3(256), 0, stream, cnt, bsum, row_ofs, wpos, chunk, N);
  hipLaunchKernelGGL(k_scatter, dim3((E+255)/256), dim3(256), 0, stream, src, dst, wpos, csr_src, E);
  hipLaunchKernelGGL(k_aggr,    dim3((N+3)/4),     dim3(256), 0, stream, h, as_, ad_, row_ofs, csr_src, bias, out, N);
}

// Round 9
// 146.521 us; speedup vs baseline: 1.0003x; 1.0003x over previous
//
#include <hip/hip_runtime.h>
#include <hip/hip_fp16.h>

#define HD 8
#define CD 16
#define DIM 128
#define NEG_SLOPE 0.2f

static __device__ __forceinline__ float lrelu(float v){ return v > 0.f ? v : NEG_SLOPE*v; }

// ---------------- K1: h = x @ W (fp16 out), plus alpha_src/alpha_dst epilogue ----------------
// 64-node tile + register double-buffer prefetch of W.
// __launch_bounds__(256, 3): grid is 782 blocks = 3 blocks/CU (grid-limited), so cap the
// allocator at 3 waves/SIMD (~170 VGPR) instead of its default max-occupancy target —
// r8 showed it allocated only 52 VGPR, defeating the W prefetch and serializing every
// ds_read. Register slack costs zero occupancy here.
__global__ __launch_bounds__(256, 3) void k_gemm(const float* __restrict__ x,
    const float* __restrict__ W, const float* __restrict__ a_src_g, const float* __restrict__ a_dst_g,
    __half* __restrict__ hout, float* __restrict__ as_o, float* __restrict__ ad_o, int N)
{
  __shared__ float xs[64*DIM]; // 32 KB
  const int tid = threadIdx.x;
  const int c = tid & 31;
  const int r = tid >> 5;
  const long nbase = (long)blockIdx.x * 64;

  #pragma unroll
  for (int it = 0; it < 8; ++it){
    int lin = it*1024 + tid*4;
    long node = nbase + (lin >> 7);
    float4 v = make_float4(0.f,0.f,0.f,0.f);
    if (node < N) v = *(const float4*)(x + node*DIM + (lin & 127));
    *(float4*)(xs + lin) = v;
  }
  __syncthreads();

  float acc[8][4];
  #pragma unroll
  for (int i = 0; i < 8; ++i){ acc[i][0]=0.f; acc[i][1]=0.f; acc[i][2]=0.f; acc[i][3]=0.f; }

  const float* Wc = W + 4*c;
  float4 w0 = *(const float4*)(Wc + 0*DIM);
  float4 w1 = *(const float4*)(Wc + 1*DIM);
  float4 w2 = *(const float4*)(Wc + 2*DIM);
  float4 w3 = *(const float4*)(Wc + 3*DIM);

#define FMA_STEP(kk)                                                        \
  {                                                                         \
    _Pragma("unroll")                                                       \
    for (int i = 0; i < 8; ++i){                                            \
      float4 xv = *(const float4*)(xs + (r*8+i)*DIM + (kk));                \
      acc[i][0] += xv.x*w0.x + xv.y*w1.x + xv.z*w2.x + xv.w*w3.x;           \
      acc[i][1] += xv.x*w0.y + xv.y*w1.y + xv.z*w2.y + xv.w*w3.y;           \
      acc[i][2] += xv.x*w0.z + xv.y*w1.z + xv.z*w2.z + xv.w*w3.z;           \
      acc[i][3] += xv.x*w0.w + xv.y*w1.w + xv.z*w2.w + xv.w*w3.w;           \
    }                                                                       \
  }

  for (int k = 0; k < DIM-4; k += 4){
    float4 nw0 = *(const float4*)(Wc + (size_t)(k+4)*DIM);
    float4 nw1 = *(const float4*)(Wc + (size_t)(k+5)*DIM);
    float4 nw2 = *(const float4*)(Wc + (size_t)(k+6)*DIM);
    float4 nw3 = *(const float4*)(Wc + (size_t)(k+7)*DIM);
    FMA_STEP(k);
    w0 = nw0; w1 = nw1; w2 = nw2; w3 = nw3;
  }
  FMA_STEP(DIM-4);
#undef FMA_STEP

  float4 asv = *(const float4*)(a_src_g + 4*c);
  float4 adv = *(const float4*)(a_dst_g + 4*c);
  #pragma unroll
  for (int i = 0; i < 8; ++i){
    long node = nbase + r*8 + i;
    float ps = acc[i][0]*asv.x + acc[i][1]*asv.y + acc[i][2]*asv.z + acc[i][3]*asv.w;
    float pd = acc[i][0]*adv.x + acc[i][1]*adv.y + acc[i][2]*adv.z + acc[i][3]*adv.w;
    ps += __shfl_xor(ps, 1); ps += __shfl_xor(ps, 2);
    pd += __shfl_xor(pd, 1); pd += __shfl_xor(pd, 2);
    if (node < N){
      union { __half2 h2[2]; uint2 u; } pk;
      pk.h2[0] = __floats2half2_rn(acc[i][0], acc[i][1]);
      pk.h2[1] = __floats2half2_rn(acc[i][2], acc[i][3]);
      *(uint2*)(hout + node*DIM + 4*c) = pk.u;
      if ((c & 3) == 0){
        as_o[node*HD + (c>>2)] = ps;
        ad_o[node*HD + (c>>2)] = pd;
      }
    }
  }
}

// ---------------- CSR build ----------------
__global__ void k_count(const int* __restrict__ dst, int* __restrict__ cnt, int E){
  int e = blockIdx.x*256 + threadIdx.x;
  if (e < E) atomicAdd(&cnt[dst[e]], 1);
}

__global__ __launch_bounds__(256) void k_scan1(const int* __restrict__ cnt, int* __restrict__ bsum,
                                               int chunk, int N){
  __shared__ int tmp[256];
  int t = threadIdx.x;
  int base = blockIdx.x * chunk;
  int i = base + t;
  int v = (t < chunk && i < N) ? cnt[i] : 0;
  tmp[t] = v; __syncthreads();
  for (int off = 128; off > 0; off >>= 1){
    if (t < off) tmp[t] += tmp[t+off];
    __syncthreads();
  }
  if (t == 0) bsum[blockIdx.x] = tmp[0];
}

__global__ __launch_bounds__(256) void k_scan2(int* __restrict__ bsum, int* __restrict__ row_ofs, int N){
  __shared__ int tmp[256];
  int t = threadIdx.x;
  int v = bsum[t];
  tmp[t] = v; __syncthreads();
  for (int off = 1; off < 256; off <<= 1){
    int u = (t >= off) ? tmp[t-off] : 0;
    __syncthreads();
    tmp[t] += u;
    __syncthreads();
  }
  bsum[t] = tmp[t] - v;            // exclusive
  if (t == 255) row_ofs[N] = tmp[255];
}

__global__ __launch_bounds__(256) void k_scan3(const int* __restrict__ cnt, const int* __restrict__ bsum,
                                               int* __restrict__ row_ofs, int* __restrict__ wpos,
                                               int chunk, int N){
  __shared__ int tmp[256];
  int t = threadIdx.x;
  int base = blockIdx.x * chunk;
  int i = base + t;
  int v = (t < chunk && i < N) ? cnt[i] : 0;
  tmp[t] = v; __syncthreads();
  for (int off = 1; off < 256; off <<= 1){
    int u = (t >= off) ? tmp[t-off] : 0;
    __syncthreads();
    tmp[t] += u;
    __syncthreads();
  }
  int excl = tmp[t] - v;
  int bbase = bsum[blockIdx.x];
  if (t < chunk && i < N){
    row_ofs[i] = bbase + excl;
    wpos[i]    = bbase + excl;
  }
}

// scatter edges into CSR order — src index ONLY (weights recomputed in k_aggr).
__global__ void k_scatter(const int* __restrict__ src, const int* __restrict__ dst,
                          int* __restrict__ wpos, int* __restrict__ csr_src, int E){
  int e = blockIdx.x*256 + threadIdx.x;
  if (e >= E) return;
  int d = dst[e];
  int pos = atomicAdd(&wpos[d], 1);
  csr_src[pos] = src[e];
}

// ---------------- K4: weighted gather (fp16 h), weights computed per-lane ----------------
__global__ __launch_bounds__(256) void k_aggr(const __half* __restrict__ h,
    const float* __restrict__ as_, const float* __restrict__ ad_,
    const int* __restrict__ row_ofs, const int* __restrict__ csr_src,
    const float* __restrict__ bias, float* __restrict__ out, int N)
{
  const int n = blockIdx.x*4 + (threadIdx.x >> 6);
  if (n >= N) return;
  const int t  = threadIdx.x & 63;
  const int hb = t >> 3;
  const int off = t*2;

  const float ad_n = ad_[(size_t)n*HD + hb];
  const float w_self = __expf(lrelu(as_[(size_t)n*HD + hb] + ad_n));

  float sum = w_self;
  float2 hv = __half22float2(*(const __half2*)(h + (size_t)n*DIM + off));
  float2 acc; acc.x = w_self*hv.x; acc.y = w_self*hv.y;

  const int ofs = row_ofs[n];
  const int deg = row_ofs[n+1] - ofs;

  for (int jb = 0; jb < deg; jb += 16){
    const int c = deg - jb;               // valid slots this chunk (>=1)
    int s[16];
    #pragma unroll
    for (int q = 0; q < 16; ++q){
      int sq = csr_src[ofs + jb + q];     // padded: safe to over-read
      s[q] = (q < c) ? sq : n;
    }

    __half2 hq[16];                        // 16 independent gathers, 1 VGPR each
    #pragma unroll
    for (int q = 0; q < 16; ++q)
      hq[q] = *(const __half2*)(h + (size_t)s[q]*DIM + off);

    float w[16];
    #pragma unroll
    for (int q = 0; q < 16; ++q){
      float e = lrelu(as_[(size_t)s[q]*HD + hb] + ad_n);
      w[q] = (q < c) ? __expf(e) : 0.f;
    }

    #pragma unroll
    for (int q = 0; q < 16; ++q){
      float2 hf = __half22float2(hq[q]);
      sum   += w[q];
      acc.x += w[q]*hf.x;
      acc.y += w[q]*hf.y;
    }
  }

  const float2 bv = *(const float2*)(bias + off);
  const float inv = 1.0f / (sum + 1e-16f);
  float2 o;
  o.x = acc.x*inv + bv.x;
  o.y = acc.y*inv + bv.y;
  *(float2*)(out + (size_t)n*DIM + off) = o;
}

extern "C" void kernel_launch(void* const* d_in, const int* in_sizes, int n_in,
                              void* d_out, int out_size, void* d_ws, size_t ws_size,
                              hipStream_t stream)
{
  const float* x     = (const float*)d_in[0];
  const int*   ei    = (const int*)  d_in[1];
  const float* W     = (const float*)d_in[2];
  const float* a_src = (const float*)d_in[3];
  const float* a_dst = (const float*)d_in[4];
  const float* bias  = (const float*)d_in[5];
  float* out = (float*)d_out;

  const int N = in_sizes[0] / DIM;
  const int E = in_sizes[1] / 2;
  const int* src = ei;
  const int* dst = ei + E;

  char* w = (char*)d_ws;
  __half* h    = (__half*)w; w += (size_t)N*DIM*2;
  float* as_   = (float*)w; w += (size_t)N*HD*4;
  float* ad_   = (float*)w; w += (size_t)N*HD*4;
  int* csr_src = (int*)w;   w += (size_t)(E+16)*4;     // +16 pad for chunk over-read
  int* cnt     = (int*)w;   w += (size_t)N*4;
  int* wpos    = (int*)w;   w += (size_t)N*4;
  int* bsum    = (int*)w;   w += 256*4;
  int* row_ofs = (int*)w;   w += (size_t)(N+1)*4;

  const int chunk = (N + 255) / 256;   // 196 for N=50000 (must be <=256)

  hipLaunchKernelGGL(k_gemm,    dim3((N+63)/64),   dim3(256), 0, stream, x, W, a_src, a_dst, h, as_, ad_, N);
  hipMemsetAsync(cnt, 0, (size_t)N*4, stream);
  hipLaunchKernelGGL(k_count,   dim3((E+255)/256), dim3(256), 0, stream, dst, cnt, E);
  hipLaunchKernelGGL(k_scan1,   dim3(256),         dim3(256), 0, stream, cnt, bsum, chunk, N);
  hipLaunchKernelGGL(k_scan2,   dim3(1),           dim3(256), 0, stream, bsum, row_ofs, N);
  hipLaunchKernelGGL(k_scan3,   dim3(256),         dim3(256), 0, stream, cnt, bsum, row_ofs, wpos, chunk, N);
  hipLaunchKernelGGL(k_scatter, dim3((E+255)/256), dim3(256), 0, stream, src, dst, wpos, csr_src, E);
  hipLaunchKernelGGL(k_aggr,    dim3((N+3)/4),     dim3(256), 0, stream, h, as_, ad_, row_ofs, csr_src, bias, out, N);
}

// Round 10
// 141.266 us; speedup vs baseline: 1.0375x; 1.0372x over previous
//
#include <hip/hip_runtime.h>
#include <hip/hip_fp16.h>

#define HD 8
#define CD 16
#define DIM 128
#define NEG_SLOPE 0.2f

typedef __attribute__((ext_vector_type(8))) _Float16 f16x8;
typedef __attribute__((ext_vector_type(4))) float    f32x4;

static __device__ __forceinline__ float lrelu(float v){ return v > 0.f ? v : NEG_SLOPE*v; }

// ---------------- K0: W fp32 [k][c] -> Wt fp16 [c][k] (B^T layout for MFMA) ----------------
__global__ __launch_bounds__(256) void k_wprep(const float* __restrict__ W, __half* __restrict__ Wt){
  int idx = blockIdx.x*256 + threadIdx.x;      // 16384 elements
  if (idx < DIM*DIM){
    int k = idx >> 7, c = idx & 127;
    Wt[(size_t)c*DIM + k] = __float2half(W[idx]);
  }
}

// ---------------- K1: h = x @ W via MFMA fp16, + alpha epilogue ----------------
// 64 nodes/block, 4 waves. Wave wv owns nodes wv*16..wv*16+15.
// A-frag (x): lane&15 = row, k = ks*32 + 8*(lane>>4) + j  (8 contiguous fp16 from LDS).
// B-frag (Wt, [col][k] row-major): lane&15 = col, same k pattern (16B global, L1-hot).
// D: row = (lane>>4)*4 + i, col = t*16 + (lane&15). Col-tile t == head t (16-aligned).
__global__ __launch_bounds__(256, 3) void k_gemm(const float* __restrict__ x,
    const __half* __restrict__ Wt, const float* __restrict__ a_src_g, const float* __restrict__ a_dst_g,
    __half* __restrict__ hout, float* __restrict__ as_o, float* __restrict__ ad_o, int N)
{
  __shared__ __half xs[64*136];                // pad 128->136: breaks LDS bank aliasing
  const int tid  = threadIdx.x;
  const int lane = tid & 63;
  const int wv   = tid >> 6;
  const long nbase = (long)blockIdx.x * 64;

  // stage x (fp32 global, coalesced) -> fp16 LDS
  #pragma unroll
  for (int it = 0; it < 8; ++it){
    int lin = it*1024 + tid*4;
    int row = lin >> 7, col = lin & 127;
    long node = nbase + row;
    float4 v = make_float4(0.f,0.f,0.f,0.f);
    if (node < N) v = *(const float4*)(x + node*DIM + col);
    __half2* dst = (__half2*)(xs + row*136 + col);
    dst[0] = __floats2half2_rn(v.x, v.y);
    dst[1] = __floats2half2_rn(v.z, v.w);
  }
  __syncthreads();

  const int lrow = lane & 15;
  const int g    = lane >> 4;

  f16x8 af[4];
  #pragma unroll
  for (int ks = 0; ks < 4; ++ks)
    af[ks] = *(const f16x8*)(xs + (wv*16 + lrow)*136 + ks*32 + g*8);

  f32x4 accs[8];
  #pragma unroll
  for (int t = 0; t < 8; ++t){
    f32x4 acc = {0.f,0.f,0.f,0.f};
    #pragma unroll
    for (int ks = 0; ks < 4; ++ks){
      f16x8 bf = *(const f16x8*)(Wt + (size_t)(t*16 + lrow)*DIM + ks*32 + g*8);
      acc = __builtin_amdgcn_mfma_f32_16x16x32_f16(af[ks], bf, acc, 0, 0, 0);
    }
    accs[t] = acc;
  }

  // D -> LDS as fp16 h (reuse xs; wave touches only its own 16 rows, no sync needed)
  #pragma unroll
  for (int t = 0; t < 8; ++t)
    #pragma unroll
    for (int i = 0; i < 4; ++i)
      xs[(wv*16 + g*4 + i)*136 + t*16 + lrow] = __float2half(accs[t][i]);
  __syncthreads();

  // phase 2a: coalesced h store (uint4 = 8 halves)
  #pragma unroll
  for (int j = 0; j < 4; ++j){
    int idx = j*256 + tid;                     // 1024 segments of 16B
    int row = idx >> 4, seg = idx & 15;
    long node = nbase + row;
    if (node < N){
      uint4 v = *(const uint4*)((const char*)xs + row*272 + seg*16);
      *(uint4*)(hout + node*DIM + seg*8) = v;
    }
  }
  // phase 2b: alpha dots from LDS h (head hd = col-tile)
  #pragma unroll
  for (int j = 0; j < 2; ++j){
    int idx = j*256 + tid;                     // 512 (node,head) pairs
    int row = idx >> 3, hd = idx & 7;
    long node = nbase + row;
    if (node < N){
      const __half* hp = xs + row*136 + hd*16;
      float ps = 0.f, pd = 0.f;
      #pragma unroll
      for (int cc = 0; cc < 16; ++cc){
        float hv = __half2float(hp[cc]);
        ps += hv * a_src_g[hd*16 + cc];
        pd += hv * a_dst_g[hd*16 + cc];
      }
      as_o[node*HD + hd] = ps;
      ad_o[node*HD + hd] = pd;
    }
  }
}

// ---------------- CSR build ----------------
__global__ void k_count(const int* __restrict__ dst, int* __restrict__ cnt, int E){
  int e = blockIdx.x*256 + threadIdx.x;
  if (e < E) atomicAdd(&cnt[dst[e]], 1);
}

__global__ __launch_bounds__(256) void k_scan1(const int* __restrict__ cnt, int* __restrict__ bsum,
                                               int chunk, int N){
  __shared__ int tmp[256];
  int t = threadIdx.x;
  int base = blockIdx.x * chunk;
  int i = base + t;
  int v = (t < chunk && i < N) ? cnt[i] : 0;
  tmp[t] = v; __syncthreads();
  for (int off = 128; off > 0; off >>= 1){
    if (t < off) tmp[t] += tmp[t+off];
    __syncthreads();
  }
  if (t == 0) bsum[blockIdx.x] = tmp[0];
}

__global__ __launch_bounds__(256) void k_scan2(int* __restrict__ bsum, int* __restrict__ row_ofs, int N){
  __shared__ int tmp[256];
  int t = threadIdx.x;
  int v = bsum[t];
  tmp[t] = v; __syncthreads();
  for (int off = 1; off < 256; off <<= 1){
    int u = (t >= off) ? tmp[t-off] : 0;
    __syncthreads();
    tmp[t] += u;
    __syncthreads();
  }
  bsum[t] = tmp[t] - v;            // exclusive
  if (t == 255) row_ofs[N] = tmp[255];
}

__global__ __launch_bounds__(256) void k_scan3(const int* __restrict__ cnt, const int* __restrict__ bsum,
                                               int* __restrict__ row_ofs, int* __restrict__ wpos,
                                               int chunk, int N){
  __shared__ int tmp[256];
  int t = threadIdx.x;
  int base = blockIdx.x * chunk;
  int i = base + t;
  int v = (t < chunk && i < N) ? cnt[i] : 0;
  tmp[t] = v; __syncthreads();
  for (int off = 1; off < 256; off <<= 1){
    int u = (t >= off) ? tmp[t-off] : 0;
    __syncthreads();
    tmp[t] += u;
    __syncthreads();
  }
  int excl = tmp[t] - v;
  int bbase = bsum[blockIdx.x];
  if (t < chunk && i < N){
    row_ofs[i] = bbase + excl;
    wpos[i]    = bbase + excl;
  }
}

// scatter edges into CSR order — src index ONLY (weights recomputed in k_aggr).
__global__ void k_scatter(const int* __restrict__ src, const int* __restrict__ dst,
                          int* __restrict__ wpos, int* __restrict__ csr_src, int E){
  int e = blockIdx.x*256 + threadIdx.x;
  if (e >= E) return;
  int d = dst[e];
  int pos = atomicAdd(&wpos[d], 1);
  csr_src[pos] = src[e];
}

// ---------------- K4: weighted gather (fp16 h), weights computed per-lane ----------------
__global__ __launch_bounds__(256) void k_aggr(const __half* __restrict__ h,
    const float* __restrict__ as_, const float* __restrict__ ad_,
    const int* __restrict__ row_ofs, const int* __restrict__ csr_src,
    const float* __restrict__ bias, float* __restrict__ out, int N)
{
  const int n = blockIdx.x*4 + (threadIdx.x >> 6);
  if (n >= N) return;
  const int t  = threadIdx.x & 63;
  const int hb = t >> 3;
  const int off = t*2;

  const float ad_n = ad_[(size_t)n*HD + hb];
  const float w_self = __expf(lrelu(as_[(size_t)n*HD + hb] + ad_n));

  float sum = w_self;
  float2 hv = __half22float2(*(const __half2*)(h + (size_t)n*DIM + off));
  float2 acc; acc.x = w_self*hv.x; acc.y = w_self*hv.y;

  const int ofs = row_ofs[n];
  const int deg = row_ofs[n+1] - ofs;

  for (int jb = 0; jb < deg; jb += 16){
    const int c = deg - jb;               // valid slots this chunk (>=1)
    int s[16];
    #pragma unroll
    for (int q = 0; q < 16; ++q){
      int sq = csr_src[ofs + jb + q];     // padded: safe to over-read
      s[q] = (q < c) ? sq : n;
    }

    __half2 hq[16];                        // 16 independent gathers, 1 VGPR each
    #pragma unroll
    for (int q = 0; q < 16; ++q)
      hq[q] = *(const __half2*)(h + (size_t)s[q]*DIM + off);

    float w[16];
    #pragma unroll
    for (int q = 0; q < 16; ++q){
      float e = lrelu(as_[(size_t)s[q]*HD + hb] + ad_n);
      w[q] = (q < c) ? __expf(e) : 0.f;
    }

    #pragma unroll
    for (int q = 0; q < 16; ++q){
      float2 hf = __half22float2(hq[q]);
      sum   += w[q];
      acc.x += w[q]*hf.x;
      acc.y += w[q]*hf.y;
    }
  }

  const float2 bv = *(const float2*)(bias + off);
  const float inv = 1.0f / (sum + 1e-16f);
  float2 o;
  o.x = acc.x*inv + bv.x;
  o.y = acc.y*inv + bv.y;
  *(float2*)(out + (size_t)n*DIM + off) = o;
}

extern "C" void kernel_launch(void* const* d_in, const int* in_sizes, int n_in,
                              void* d_out, int out_size, void* d_ws, size_t ws_size,
                              hipStream_t stream)
{
  const float* x     = (const float*)d_in[0];
  const int*   ei    = (const int*)  d_in[1];
  const float* W     = (const float*)d_in[2];
  const float* a_src = (const float*)d_in[3];
  const float* a_dst = (const float*)d_in[4];
  const float* bias  = (const float*)d_in[5];
  float* out = (float*)d_out;

  const int N = in_sizes[0] / DIM;
  const int E = in_sizes[1] / 2;
  const int* src = ei;
  const int* dst = ei + E;

  char* w = (char*)d_ws;
  __half* h    = (__half*)w; w += (size_t)N*DIM*2;
  __half* Wt   = (__half*)w; w += (size_t)DIM*DIM*2;
  float* as_   = (float*)w; w += (size_t)N*HD*4;
  float* ad_   = (float*)w; w += (size_t)N*HD*4;
  int* csr_src = (int*)w;   w += (size_t)(E+16)*4;     // +16 pad for chunk over-read
  int* cnt     = (int*)w;   w += (size_t)N*4;
  int* wpos    = (int*)w;   w += (size_t)N*4;
  int* bsum    = (int*)w;   w += 256*4;
  int* row_ofs = (int*)w;   w += (size_t)(N+1)*4;

  const int chunk = (N + 255) / 256;   // 196 for N=50000 (must be <=256)

  hipLaunchKernelGGL(k_wprep,   dim3(64),          dim3(256), 0, stream, W, Wt);
  hipLaunchKernelGGL(k_gemm,    dim3((N+63)/64),   dim3(256), 0, stream, x, Wt, a_src, a_dst, h, as_, ad_, N);
  hipMemsetAsync(cnt, 0, (size_t)N*4, stream);
  hipLaunchKernelGGL(k_count,   dim3((E+255)/256), dim3(256), 0, stream, dst, cnt, E);
  hipLaunchKernelGGL(k_scan1,   dim3(256),         dim3(256), 0, stream, cnt, bsum, chunk, N);
  hipLaunchKernelGGL(k_scan2,   dim3(1),           dim3(256), 0, stream, bsum, row_ofs, N);
  hipLaunchKernelGGL(k_scan3,   dim3(256),         dim3(256), 0, stream, cnt, bsum, row_ofs, wpos, chunk, N);
  hipLaunchKernelGGL(k_scatter, dim3((E+255)/256), dim3(256), 0, stream, src, dst, wpos, csr_src, E);
  hipLaunchKernelGGL(k_aggr,    dim3((N+3)/4),     dim3(256), 0, stream, h, as_, ad_, row_ofs, csr_src, bias, out, N);
}

// Round 12
// 138.429 us; speedup vs baseline: 1.0588x; 1.0205x over previous
//
#include <hip/hip_runtime.h>
#include <hip/hip_fp16.h>

#define HD 8
#define CD 16
#define DIM 128
#define NEG_SLOPE 0.2f

typedef __attribute__((ext_vector_type(8))) _Float16 f16x8;
typedef __attribute__((ext_vector_type(4))) float    f32x4;

static __device__ __forceinline__ float lrelu(float v){ return v > 0.f ? v : NEG_SLOPE*v; }

// ---------------- K0: W fp32 [k][c] -> Wt fp16 [c][k] (B^T layout for MFMA) ----------------
__global__ __launch_bounds__(256) void k_wprep(const float* __restrict__ W, __half* __restrict__ Wt){
  int idx = blockIdx.x*256 + threadIdx.x;      // 16384 elements
  if (idx < DIM*DIM){
    int k = idx >> 7, c = idx & 127;
    Wt[(size_t)c*DIM + k] = __float2half(W[idx]);
  }
}

// ---------------- K1: h = x @ W via MFMA fp16, + alpha epilogue ----------------
// 64 nodes/block, 4 waves. Wave wv owns nodes wv*16..wv*16+15.
// A-frag (x): lane&15 = row, k = ks*32 + 8*(lane>>4) + j  (8 contiguous fp16 from LDS).
// B-frag (Wt, [col][k] row-major): lane&15 = col, same k pattern (16B global, L1-hot).
// D: row = (lane>>4)*4 + i, col = t*16 + (lane&15). Col-tile t == head t (16-aligned).
__global__ __launch_bounds__(256, 3) void k_gemm(const float* __restrict__ x,
    const __half* __restrict__ Wt, const float* __restrict__ a_src_g, const float* __restrict__ a_dst_g,
    __half* __restrict__ hout, float* __restrict__ as_o, float* __restrict__ ad_o, int N)
{
  __shared__ __half xs[64*136];                // pad 128->136: breaks LDS bank aliasing
  const int tid  = threadIdx.x;
  const int lane = tid & 63;
  const int wv   = tid >> 6;
  const long nbase = (long)blockIdx.x * 64;

  // stage x (fp32 global, coalesced) -> fp16 LDS
  #pragma unroll
  for (int it = 0; it < 8; ++it){
    int lin = it*1024 + tid*4;
    int row = lin >> 7, col = lin & 127;
    long node = nbase + row;
    float4 v = make_float4(0.f,0.f,0.f,0.f);
    if (node < N) v = *(const float4*)(x + node*DIM + col);
    __half2* dst = (__half2*)(xs + row*136 + col);
    dst[0] = __floats2half2_rn(v.x, v.y);
    dst[1] = __floats2half2_rn(v.z, v.w);
  }
  __syncthreads();

  const int lrow = lane & 15;
  const int g    = lane >> 4;

  f16x8 af[4];
  #pragma unroll
  for (int ks = 0; ks < 4; ++ks)
    af[ks] = *(const f16x8*)(xs + (wv*16 + lrow)*136 + ks*32 + g*8);

  f32x4 accs[8];
  #pragma unroll
  for (int t = 0; t < 8; ++t){
    f32x4 acc = {0.f,0.f,0.f,0.f};
    #pragma unroll
    for (int ks = 0; ks < 4; ++ks){
      f16x8 bf = *(const f16x8*)(Wt + (size_t)(t*16 + lrow)*DIM + ks*32 + g*8);
      acc = __builtin_amdgcn_mfma_f32_16x16x32_f16(af[ks], bf, acc, 0, 0, 0);
    }
    accs[t] = acc;
  }

  // D -> LDS as fp16 h (reuse xs; wave touches only its own 16 rows, no sync needed)
  #pragma unroll
  for (int t = 0; t < 8; ++t)
    #pragma unroll
    for (int i = 0; i < 4; ++i)
      xs[(wv*16 + g*4 + i)*136 + t*16 + lrow] = __float2half(accs[t][i]);
  __syncthreads();

  // phase 2a: coalesced h store (uint4 = 8 halves)
  #pragma unroll
  for (int j = 0; j < 4; ++j){
    int idx = j*256 + tid;                     // 1024 segments of 16B
    int row = idx >> 4, seg = idx & 15;
    long node = nbase + row;
    if (node < N){
      uint4 v = *(const uint4*)((const char*)xs + row*272 + seg*16);
      *(uint4*)(hout + node*DIM + seg*8) = v;
    }
  }
  // phase 2b: alpha dots from LDS h (head hd = col-tile)
  #pragma unroll
  for (int j = 0; j < 2; ++j){
    int idx = j*256 + tid;                     // 512 (node,head) pairs
    int row = idx >> 3, hd = idx & 7;
    long node = nbase + row;
    if (node < N){
      const __half* hp = xs + row*136 + hd*16;
      float ps = 0.f, pd = 0.f;
      #pragma unroll
      for (int cc = 0; cc < 16; ++cc){
        float hv = __half2float(hp[cc]);
        ps += hv * a_src_g[hd*16 + cc];
        pd += hv * a_dst_g[hd*16 + cc];
      }
      as_o[node*HD + hd] = ps;
      ad_o[node*HD + hd] = pd;
    }
  }
}

// ---------------- CSR build ----------------
// hand-rolled zero kernel: the ROCm runtime's fillBufferAligned path for this
// size ran at 4.6 GB/s (43 us for 200 KB, r10 counters) — in-stream, serialized.
__global__ void k_zero(int* __restrict__ p, int n){
  int i = blockIdx.x*256 + threadIdx.x;
  if (i < n) p[i] = 0;
}

__global__ void k_count(const int* __restrict__ dst, int* __restrict__ cnt, int E){
  int e = blockIdx.x*256 + threadIdx.x;
  if (e < E) atomicAdd(&cnt[dst[e]], 1);
}

__global__ __launch_bounds__(256) void k_scan1(const int* __restrict__ cnt, int* __restrict__ bsum,
                                               int chunk, int N){
  __shared__ int tmp[256];
  int t = threadIdx.x;
  int base = blockIdx.x * chunk;
  int i = base + t;
  int v = (t < chunk && i < N) ? cnt[i] : 0;
  tmp[t] = v; __syncthreads();
  for (int off = 128; off > 0; off >>= 1){
    if (t < off) tmp[t] += tmp[t+off];
    __syncthreads();
  }
  if (t == 0) bsum[blockIdx.x] = tmp[0];
}

__global__ __launch_bounds__(256) void k_scan2(int* __restrict__ bsum, int* __restrict__ row_ofs, int N){
  __shared__ int tmp[256];
  int t = threadIdx.x;
  int v = bsum[t];
  tmp[t] = v; __syncthreads();
  for (int off = 1; off < 256; off <<= 1){
    int u = (t >= off) ? tmp[t-off] : 0;
    __syncthreads();
    tmp[t] += u;
    __syncthreads();
  }
  bsum[t] = tmp[t] - v;            // exclusive
  if (t == 255) row_ofs[N] = tmp[255];
}

__global__ __launch_bounds__(256) void k_scan3(const int* __restrict__ cnt, const int* __restrict__ bsum,
                                               int* __restrict__ row_ofs, int* __restrict__ wpos,
                                               int chunk, int N){
  __shared__ int tmp[256];
  int t = threadIdx.x;
  int base = blockIdx.x * chunk;
  int i = base + t;
  int v = (t < chunk && i < N) ? cnt[i] : 0;
  tmp[t] = v; __syncthreads();
  for (int off = 1; off < 256; off <<= 1){
    int u = (t >= off) ? tmp[t-off] : 0;
    __syncthreads();
    tmp[t] += u;
    __syncthreads();
  }
  int excl = tmp[t] - v;
  int bbase = bsum[blockIdx.x];
  if (t < chunk && i < N){
    row_ofs[i] = bbase + excl;
    wpos[i]    = bbase + excl;
  }
}

// scatter edges into CSR order — src index ONLY (weights recomputed in k_aggr).
__global__ void k_scatter(const int* __restrict__ src, const int* __restrict__ dst,
                          int* __restrict__ wpos, int* __restrict__ csr_src, int E){
  int e = blockIdx.x*256 + threadIdx.x;
  if (e >= E) return;
  int d = dst[e];
  int pos = atomicAdd(&wpos[d], 1);
  csr_src[pos] = src[e];
}

// ---------------- K4: weighted gather (fp16 h), weights computed per-lane ----------------
__global__ __launch_bounds__(256) void k_aggr(const __half* __restrict__ h,
    const float* __restrict__ as_, const float* __restrict__ ad_,
    const int* __restrict__ row_ofs, const int* __restrict__ csr_src,
    const float* __restrict__ bias, float* __restrict__ out, int N)
{
  const int n = blockIdx.x*4 + (threadIdx.x >> 6);
  if (n >= N) return;
  const int t  = threadIdx.x & 63;
  const int hb = t >> 3;
  const int off = t*2;

  const float ad_n = ad_[(size_t)n*HD + hb];
  const float w_self = __expf(lrelu(as_[(size_t)n*HD + hb] + ad_n));

  float sum = w_self;
  float2 hv = __half22float2(*(const __half2*)(h + (size_t)n*DIM + off));
  float2 acc; acc.x = w_self*hv.x; acc.y = w_self*hv.y;

  const int ofs = row_ofs[n];
  const int deg = row_ofs[n+1] - ofs;

  for (int jb = 0; jb < deg; jb += 16){
    const int c = deg - jb;               // valid slots this chunk (>=1)
    int s[16];
    #pragma unroll
    for (int q = 0; q < 16; ++q){
      int sq = csr_src[ofs + jb + q];     // padded: safe to over-read
      s[q] = (q < c) ? sq : n;
    }

    __half2 hq[16];                        // 16 independent gathers, 1 VGPR each
    #pragma unroll
    for (int q = 0; q < 16; ++q)
      hq[q] = *(const __half2*)(h + (size_t)s[q]*DIM + off);

    float w[16];
    #pragma unroll
    for (int q = 0; q < 16; ++q){
      float e = lrelu(as_[(size_t)s[q]*HD + hb] + ad_n);
      w[q] = (q < c) ? __expf(e) : 0.f;
    }

    #pragma unroll
    for (int q = 0; q < 16; ++q){
      float2 hf = __half22float2(hq[q]);
      sum   += w[q];
      acc.x += w[q]*hf.x;
      acc.y += w[q]*hf.y;
    }
  }

  const float2 bv = *(const float2*)(bias + off);
  const float inv = 1.0f / (sum + 1e-16f);
  float2 o;
  o.x = acc.x*inv + bv.x;
  o.y = acc.y*inv + bv.y;
  *(float2*)(out + (size_t)n*DIM + off) = o;
}

extern "C" void kernel_launch(void* const* d_in, const int* in_sizes, int n_in,
                              void* d_out, int out_size, void* d_ws, size_t ws_size,
                              hipStream_t stream)
{
  const float* x     = (const float*)d_in[0];
  const int*   ei    = (const int*)  d_in[1];
  const float* W     = (const float*)d_in[2];
  const float* a_src = (const float*)d_in[3];
  const float* a_dst = (const float*)d_in[4];
  const float* bias  = (const float*)d_in[5];
  float* out = (float*)d_out;

  const int N = in_sizes[0] / DIM;
  const int E = in_sizes[1] / 2;
  const int* src = ei;
  const int* dst = ei + E;

  char* w = (char*)d_ws;
  __half* h    = (__half*)w; w += (size_t)N*DIM*2;
  __half* Wt   = (__half*)w; w += (size_t)DIM*DIM*2;
  float* as_   = (float*)w; w += (size_t)N*HD*4;
  float* ad_   = (float*)w; w += (size_t)N*HD*4;
  int* csr_src = (int*)w;   w += (size_t)(E+16)*4;     // +16 pad for chunk over-read
  int* cnt     = (int*)w;   w += (size_t)N*4;
  int* wpos    = (int*)w;   w += (size_t)N*4;
  int* bsum    = (int*)w;   w += 256*4;
  int* row_ofs = (int*)w;   w += (size_t)(N+1)*4;

  const int chunk = (N + 255) / 256;   // 196 for N=50000 (must be <=256)

  hipLaunchKernelGGL(k_wprep,   dim3(64),          dim3(256), 0, stream, W, Wt);
  hipLaunchKernelGGL(k_gemm,    dim3((N+63)/64),   dim3(256), 0, stream, x, Wt, a_src, a_dst, h, as_, ad_, N);
  hipLaunchKernelGGL(k_zero,    dim3((N+255)/256), dim3(256), 0, stream, cnt, N);
  hipLaunchKernelGGL(k_count,   dim3((E+255)/256), dim3(256), 0, stream, dst, cnt, E);
  hipLaunchKernelGGL(k_scan1,   dim3(256),         dim3(256), 0, stream, cnt, bsum, chunk, N);
  hipLaunchKernelGGL(k_scan2,   dim3(1),           dim3(256), 0, stream, bsum, row_ofs, N);
  hipLaunchKernelGGL(k_scan3,   dim3(256),         dim3(256), 0, stream, cnt, bsum, row_ofs, wpos, chunk, N);
  hipLaunchKernelGGL(k_scatter, dim3((E+255)/256), dim3(256), 0, stream, src, dst, wpos, csr_src, E);
  hipLaunchKernelGGL(k_aggr,    dim3((N+3)/4),     dim3(256), 0, stream, h, as_, ad_, row_ofs, csr_src, bias, out, N);
}